// Round 1
// baseline (691.542 us; speedup 1.0000x reference)
//
#include <hip/hip_runtime.h>

#define T_LEN 48000
#define NCH   64
#define NB    4
#define NT    1024   // conv time tile
#define CT    512    // scan chunk length
#define WU    512    // scan warm-up steps (0.96^512 ~ 8e-10, 0.99^512 ~ 6e-3)

static constexpr double DTd     = 1.0 / 48000.0;
static constexpr double ALPHAd  = DTd / (DTd + 0.0005);   // exactly 0.04
static constexpr float  AF      = (float)ALPHAd;
static constexpr float  OMF     = (float)(1.0 - ALPHAd);  // 0.96

// ---------------------------------------------------------------- K0: first nonzero tap per channel
__global__ void kstart_kernel(const float* __restrict__ Km, int* __restrict__ kstart, int L) {
    __shared__ int smin;
    if (threadIdx.x == 0) smin = L - 1;
    __syncthreads();
    const int c = blockIdx.x;
    int local = L - 1;
    for (int i = threadIdx.x; i < L; i += blockDim.x) {
        if (Km[(size_t)c * L + i] != 0.0f) { local = i; break; }
    }
    atomicMin(&smin, local);
    __syncthreads();
    if (threadIdx.x == 0) kstart[c] = smin;
}

// ---------------------------------------------------------------- K1: fp32 FIR filterbank + ReLU
// resp[b][c][t] = sum_{j=ks}^{L-1} K[c][j] * x[b][t + j - (L-1)]   (x = 0 for idx < 0)
// With q = j - ks:  resp = sum_q KW[q] * XW[t - t0 + q],  XW[i] = x[t0 + ks - (L-1) + i]
__global__ __launch_bounds__(256) void conv_kernel(
        const float* __restrict__ x, const float* __restrict__ Km,
        const int* __restrict__ kstart, float* __restrict__ rect, int L) {
    const int b  = blockIdx.x;
    const int c  = blockIdx.y;
    const int t0 = blockIdx.z * NT;
    const int ks = kstart[c];
    const int len  = L - ks;
    const int len4 = (len + 3) & ~3;

    extern __shared__ float lds[];
    float* KW = lds;            // len4 floats (zero padded)
    float* XW = lds + len4;     // NT + len4 floats

    const int   wlen = NT + len4;
    const int   base = t0 + ks - (L - 1);
    const float* xb  = x + (size_t)b * T_LEN;

    for (int i = threadIdx.x; i < len4; i += 256)
        KW[i] = (i < len) ? Km[(size_t)c * L + ks + i] : 0.0f;
    for (int i = threadIdx.x; i < wlen; i += 256) {
        const int xi = base + i;
        XW[i] = (xi >= 0 && xi < T_LEN) ? xb[xi] : 0.0f;
    }
    __syncthreads();

    const int tid = threadIdx.x;
    const float4* XW4 = (const float4*)XW;
    const float4* KW4 = (const float4*)KW;

    float a0 = 0.f, a1 = 0.f, a2 = 0.f, a3 = 0.f;
    float4 av = XW4[tid];
    const int nq = len4 >> 2;
    for (int q = 0; q < nq; ++q) {
        const float4 kv = KW4[q];
        const float4 bv = XW4[tid + q + 1];
        a0 += kv.x * av.x + kv.y * av.y + kv.z * av.z + kv.w * av.w;
        a1 += kv.x * av.y + kv.y * av.z + kv.z * av.w + kv.w * bv.x;
        a2 += kv.x * av.z + kv.y * av.w + kv.z * bv.x + kv.w * bv.y;
        a3 += kv.x * av.w + kv.y * bv.x + kv.z * bv.y + kv.w * bv.z;
        av = bv;
    }

    const int t = t0 + 4 * tid;
    if (t < T_LEN) {
        float4 r;
        r.x = fmaxf(a0, 0.0f); r.y = fmaxf(a1, 0.0f);
        r.z = fmaxf(a2, 0.0f); r.w = fmaxf(a3, 0.0f);
        *(float4*)&rect[((size_t)(b * NCH + c)) * T_LEN + t] = r;
    }
}

// ---------------------------------------------------------------- K2: fused EMA + adaptive-threshold scan
// lane = channel, 4 batches held in-lane; refractory is provably a no-op.
__device__ __forceinline__ void scan_step(float r0, float r1, float r2, float r3,
        int u, bool store, int c, float* __restrict__ out0, float* __restrict__ out1,
        float& s0, float& s1, float& s2, float& s3, float& thr) {
    s0 = AF * r0 + OMF * s0;
    s1 = AF * r1 + OMF * s1;
    s2 = AF * r2 + OMF * s2;
    s3 = AF * r3 + OMF * s3;
    const float k0 = (s0 > thr) ? 1.0f : 0.0f;
    const float k1 = (s1 > thr) ? 1.0f : 0.0f;
    const float k2 = (s2 > thr) ? 1.0f : 0.0f;
    const float k3 = (s3 > thr) ? 1.0f : 0.0f;
    const float cnt = (k0 + k1) + (k2 + k3);
    thr = thr + 0.01f * (cnt * 0.25f) + 0.01f * (0.1f - thr);
    if (store) {
        const int e  = (u >= T_LEN) ? 1 : 0;
        const int tt = u - (e ? T_LEN : 0);
        // channel_responses: out1[((b*2+e)*T + tt)*64 + c], b-stride = 2*T*64
        const int o1 = ((e * T_LEN + tt) << 6) + c;
        out1[o1]                       = s0;
        out1[o1 + 2 * T_LEN * NCH]     = s1;
        out1[o1 + 4 * T_LEN * NCH]     = s2;
        out1[o1 + 6 * T_LEN * NCH]     = s3;
        // spike_trains: out0[(b*T + tt)*128 + e*64 + c], b-stride = T*128
        const int o0 = (tt << 7) + (e << 6) + c;
        out0[o0]                       = k0;
        out0[o0 + T_LEN * 128]         = k1;
        out0[o0 + 2 * T_LEN * 128]     = k2;
        out0[o0 + 3 * T_LEN * 128]     = k3;
    }
}

#define LOAD_SG(buf, ug) do {                                                          \
    const int tt_ = ((ug) < T_LEN) ? (ug) : ((ug) - T_LEN);                            \
    _Pragma("unroll")                                                                  \
    for (int b_ = 0; b_ < 4; ++b_) {                                                   \
        const float4* p_ = (const float4*)&rect[((size_t)(b_ * NCH + c)) * T_LEN + tt_]; \
        _Pragma("unroll")                                                              \
        for (int q_ = 0; q_ < 4; ++q_) buf[b_][q_] = p_[q_];                           \
    }                                                                                  \
} while (0)

#define PROC_SG(buf, ug) do {                                                                                   \
    _Pragma("unroll")                                                                                           \
    for (int q_ = 0; q_ < 4; ++q_) {                                                                            \
        scan_step(buf[0][q_].x, buf[1][q_].x, buf[2][q_].x, buf[3][q_].x, (ug)+4*q_+0, STORE, c, out0, out1, s0,s1,s2,s3,thr); \
        scan_step(buf[0][q_].y, buf[1][q_].y, buf[2][q_].y, buf[3][q_].y, (ug)+4*q_+1, STORE, c, out0, out1, s0,s1,s2,s3,thr); \
        scan_step(buf[0][q_].z, buf[1][q_].z, buf[2][q_].z, buf[3][q_].z, (ug)+4*q_+2, STORE, c, out0, out1, s0,s1,s2,s3,thr); \
        scan_step(buf[0][q_].w, buf[1][q_].w, buf[2][q_].w, buf[3][q_].w, (ug)+4*q_+3, STORE, c, out0, out1, s0,s1,s2,s3,thr); \
    }                                                                                                           \
} while (0)

template <bool STORE>
__device__ __forceinline__ void scan_range(int from, int to, int c,
        const float* __restrict__ rect, float* __restrict__ out0, float* __restrict__ out1,
        float& s0, float& s1, float& s2, float& s3, float& thr) {
    if (from >= to) return;                // (to-from) is always a multiple of 32
    float4 bufA[4][4], bufB[4][4];
    LOAD_SG(bufA, from);
    for (int ug = from; ug < to; ug += 32) {
        LOAD_SG(bufB, ug + 16);            // prefetch covers ~16 steps of compute
        PROC_SG(bufA, ug);
        if (ug + 32 < to) LOAD_SG(bufA, ug + 32);
        PROC_SG(bufB, ug + 16);
    }
}

__global__ __launch_bounds__(64) void scan_kernel(const float* __restrict__ rect,
                                                  float* __restrict__ out) {
    const int c    = threadIdx.x;                       // channel
    const int u0   = blockIdx.x * CT;                   // global step in [0, 96000)
    const int uend = min(u0 + CT, 2 * T_LEN);
    const int w0   = (u0 >= WU) ? (u0 - WU) : 0;
    float s0 = 0.f, s1 = 0.f, s2 = 0.f, s3 = 0.f, thr = 0.1f;
    float* out0 = out;
    float* out1 = out + (size_t)NB * T_LEN * 2 * NCH;   // 24,576,000
    scan_range<false>(w0, u0,   c, rect, out0, out1, s0, s1, s2, s3, thr);
    scan_range<true >(u0, uend, c, rect, out0, out1, s0, s1, s2, s3, thr);
}

// ---------------------------------------------------------------- launch
extern "C" void kernel_launch(void* const* d_in, const int* in_sizes, int n_in,
                              void* d_out, int out_size, void* d_ws, size_t ws_size,
                              hipStream_t stream) {
    const float* x  = (const float*)d_in[0];       // [4, 48000] fp32
    const float* Km = (const float*)d_in[1];       // [64, L]    fp32
    const int L = in_sizes[1] / NCH;

    int*   kstart = (int*)d_ws;
    float* rect   = (float*)((char*)d_ws + 1024);  // [4][64][48000] fp32 = 49.15 MB

    kstart_kernel<<<NCH, 256, 0, stream>>>(Km, kstart, L);

    const int Lpad = (L + 3) & ~3;
    const size_t lds_bytes = (size_t)(2 * Lpad + NT + 16) * sizeof(float); // ~26.9 KB
    dim3 cgrid(NB, NCH, (T_LEN + NT - 1) / NT);
    conv_kernel<<<cgrid, 256, lds_bytes, stream>>>(x, Km, kstart, rect, L);

    const int nchunks = (2 * T_LEN + CT - 1) / CT; // 188
    scan_kernel<<<nchunks, 64, 0, stream>>>(rect, (float*)d_out);
}

// Round 2
// 154.720 us; speedup vs baseline: 4.4696x; 4.4696x over previous
//
#include <hip/hip_runtime.h>
#include <hip/hip_bf16.h>

#define T_LEN 48000
#define NCH   64
#define NB    4
#define CT    256    // scan chunk length
#define WU    384    // scan warm-up steps (0.96^384~2e-7, 0.99^384~0.021 -> spike flips only)

static constexpr double DTd    = 1.0 / 48000.0;
static constexpr double ALPHAd = DTd / (DTd + 0.0005);   // exactly 0.04
static constexpr float  AF     = (float)ALPHAd;
static constexpr float  OMF    = (float)(1.0 - ALPHAd);  // 0.96

typedef __attribute__((ext_vector_type(8))) short bf16x8;
typedef __attribute__((ext_vector_type(4))) float f32x4;
typedef bf16x8 bf16x8_u __attribute__((aligned(4)));     // 4B-aligned 16B load

static __device__ __forceinline__ unsigned short f2bf(float f) {
    __hip_bfloat16 h = __float2bfloat16(f);
    unsigned short u; __builtin_memcpy(&u, &h, 2);
    return u;
}

// ---------------------------------------------------------------- K0: first nonzero tap per channel
__global__ void kstart_kernel(const float* __restrict__ Km, int* __restrict__ kstart, int L) {
    __shared__ int smin;
    if (threadIdx.x == 0) smin = L - 1;
    __syncthreads();
    const int c = blockIdx.x;
    int local = L - 1;
    for (int i = threadIdx.x; i < L; i += blockDim.x) {
        if (Km[(size_t)c * L + i] != 0.0f) { local = i; break; }
    }
    atomicMin(&smin, local);
    __syncthreads();
    if (threadIdx.x == 0) kstart[c] = smin;
}

// ---------------------------------------------------------------- K1a: x -> two parity-shifted bf16 copies (zero padded)
// copy0[b][j] = x[b][j-PAD]; copy1[b][j] = x[b][j-PAD+1]
__global__ void prep_x(const float* __restrict__ x, unsigned short* __restrict__ xc,
                       int PAD, int XCAP) {
    const int idx = blockIdx.x * 256 + threadIdx.x;
    if (idx >= NB * XCAP) return;
    const int b = idx / XCAP, j = idx % XCAP;
    const float* xb = x + (size_t)b * T_LEN;
    const int t0 = j - PAD, t1 = t0 + 1;
    xc[((size_t)b * 2 + 0) * XCAP + j] = (t0 >= 0 && t0 < T_LEN) ? f2bf(xb[t0]) : (unsigned short)0;
    xc[((size_t)b * 2 + 1) * XCAP + j] = (t1 >= 0 && t1 < T_LEN) ? f2bf(xb[t1]) : (unsigned short)0;
}

// ---------------------------------------------------------------- K1b: kernels -> pre-swizzled bf16 A-fragments
// Afrag[g][s][lane][j] = K[g*16 + (lane&15)][ks_g + 32s + 8*(lane>>4) + j]  (0 beyond Lg)
__global__ void prep_a(const float* __restrict__ Km, const int* __restrict__ kstart,
                       unsigned short* __restrict__ Afrag, int L, int SMAX) {
    const int s = blockIdx.x, g = blockIdx.y, lane = threadIdx.x;
    const int ks = kstart[g * 16];
    const int Lg = L - ks;
    const int r = lane & 15, khi = lane >> 4;
    const float* kr = Km + (size_t)(g * 16 + r) * L + ks;
    const size_t off = ((size_t)(g * SMAX + s) * 64 + lane) * 8;
    #pragma unroll
    for (int jj = 0; jj < 8; ++jj) {
        const int q = 32 * s + 8 * khi + jj;
        Afrag[off + jj] = (q < Lg) ? f2bf(kr[q]) : (unsigned short)0;
    }
}

// ---------------------------------------------------------------- K2: MFMA filterbank -> rect bf16 [B][C][T]
// block: (t-tile of 64, group); wave = one batch, N_rep=4 time tiles of 16
__global__ __launch_bounds__(256) void conv_mfma(
        const unsigned short* __restrict__ xc, const unsigned short* __restrict__ Afrag,
        const int* __restrict__ kstart, unsigned short* __restrict__ rect,
        int L, int SMAX, int PAD, int XCAP) {
    const int lane = threadIdx.x & 63;
    const int b    = threadIdx.x >> 6;
    const int g    = blockIdx.y;
    const int t0   = blockIdx.x * 64;
    const int ks   = kstart[g * 16];
    const int Lg   = L - ks;
    const int nst  = (Lg + 31) >> 5;
    const int nl   = lane & 15, khi = lane >> 4;
    const int i0   = t0 + nl + 8 * khi - (Lg - 1);     // x index for (s=0, tile 0)
    const int p    = i0 & 1;                           // parity fixed across s and tiles
    const unsigned short* xp = xc + ((size_t)(b * 2 + p)) * XCAP + (PAD + i0 - p);
    const unsigned short* ap = Afrag + ((size_t)(g * SMAX) * 64 + (size_t)lane) * 8;

    f32x4 c0 = {0.f,0.f,0.f,0.f}, c1 = c0, c2 = c0, c3 = c0;
    for (int s = 0; s < nst; ++s) {
        bf16x8 av = *(const bf16x8*)ap;
        bf16x8 b0 = *(const bf16x8_u*)(xp);
        bf16x8 b1 = *(const bf16x8_u*)(xp + 16);
        bf16x8 b2 = *(const bf16x8_u*)(xp + 32);
        bf16x8 b3 = *(const bf16x8_u*)(xp + 48);
        c0 = __builtin_amdgcn_mfma_f32_16x16x32_bf16(av, b0, c0, 0, 0, 0);
        c1 = __builtin_amdgcn_mfma_f32_16x16x32_bf16(av, b1, c1, 0, 0, 0);
        c2 = __builtin_amdgcn_mfma_f32_16x16x32_bf16(av, b2, c2, 0, 0, 0);
        c3 = __builtin_amdgcn_mfma_f32_16x16x32_bf16(av, b3, c3, 0, 0, 0);
        ap += 512; xp += 32;
    }
    // D layout: col(time)=lane&15, row(channel)=4*(lane>>4)+v   [m89-verified]
    unsigned short* rp = rect + (size_t)(b * NCH + g * 16 + 4 * khi) * T_LEN + t0 + nl;
    #pragma unroll
    for (int v = 0; v < 4; ++v) {
        rp[(size_t)v * T_LEN +  0] = f2bf(fmaxf(c0[v], 0.f));
        rp[(size_t)v * T_LEN + 16] = f2bf(fmaxf(c1[v], 0.f));
        rp[(size_t)v * T_LEN + 32] = f2bf(fmaxf(c2[v], 0.f));
        rp[(size_t)v * T_LEN + 48] = f2bf(fmaxf(c3[v], 0.f));
    }
}

// ---------------------------------------------------------------- K3: fused EMA + adaptive-threshold scan
static __device__ __forceinline__ float bfw(unsigned int w, int odd) {
    return __uint_as_float(odd ? (w & 0xFFFF0000u) : (w << 16));
}
static __device__ __forceinline__ unsigned int getw(const uint4& u, int i) {
    return i == 0 ? u.x : i == 1 ? u.y : i == 2 ? u.z : u.w;  // i is compile-time
}

__device__ __forceinline__ void scan_step(float r0, float r1, float r2, float r3,
        int u, bool store, int c, float* __restrict__ out0, float* __restrict__ out1,
        float& s0, float& s1, float& s2, float& s3, float& thr) {
    s0 = AF * r0 + OMF * s0;
    s1 = AF * r1 + OMF * s1;
    s2 = AF * r2 + OMF * s2;
    s3 = AF * r3 + OMF * s3;
    const float k0 = (s0 > thr) ? 1.0f : 0.0f;
    const float k1 = (s1 > thr) ? 1.0f : 0.0f;
    const float k2 = (s2 > thr) ? 1.0f : 0.0f;
    const float k3 = (s3 > thr) ? 1.0f : 0.0f;
    const float cnt = (k0 + k1) + (k2 + k3);
    thr = thr + 0.01f * (cnt * 0.25f) + 0.01f * (0.1f - thr);
    if (store) {
        const int e  = (u >= T_LEN) ? 1 : 0;
        const int tt = u - (e ? T_LEN : 0);
        const int o1 = ((e * T_LEN + tt) << 6) + c;          // [B][2][T][C]
        out1[o1]                   = s0;
        out1[o1 + 2 * T_LEN * NCH] = s1;
        out1[o1 + 4 * T_LEN * NCH] = s2;
        out1[o1 + 6 * T_LEN * NCH] = s3;
        const int o0 = (tt << 7) + (e << 6) + c;             // [B][T][2C]
        out0[o0]                   = k0;
        out0[o0 + T_LEN * 128]     = k1;
        out0[o0 + 2 * T_LEN * 128] = k2;
        out0[o0 + 3 * T_LEN * 128] = k3;
    }
}

#define LOAD_SG(buf, ug) do {                                                          \
    const int tt_ = ((ug) < T_LEN) ? (ug) : ((ug) - T_LEN);                            \
    _Pragma("unroll")                                                                  \
    for (int b_ = 0; b_ < 4; ++b_) {                                                   \
        const uint4* p_ = (const uint4*)(rect + (size_t)(b_ * NCH + c) * T_LEN + tt_); \
        buf[b_][0] = p_[0];                                                            \
        buf[b_][1] = p_[1];                                                            \
    }                                                                                  \
} while (0)

#define PROC_SG(buf, ug) do {                                                          \
    _Pragma("unroll")                                                                  \
    for (int q_ = 0; q_ < 16; ++q_) {                                                  \
        const float r0_ = bfw(getw(buf[0][q_ >> 3], (q_ >> 1) & 3), q_ & 1);           \
        const float r1_ = bfw(getw(buf[1][q_ >> 3], (q_ >> 1) & 3), q_ & 1);           \
        const float r2_ = bfw(getw(buf[2][q_ >> 3], (q_ >> 1) & 3), q_ & 1);           \
        const float r3_ = bfw(getw(buf[3][q_ >> 3], (q_ >> 1) & 3), q_ & 1);           \
        scan_step(r0_, r1_, r2_, r3_, (ug) + q_, STORE, c, out0, out1, s0, s1, s2, s3, thr); \
    }                                                                                  \
} while (0)

template <bool STORE>
__device__ __forceinline__ void scan_range(int from, int to, int c,
        const unsigned short* __restrict__ rect, float* __restrict__ out0, float* __restrict__ out1,
        float& s0, float& s1, float& s2, float& s3, float& thr) {
    if (from >= to) return;                // (to-from) is a multiple of 32
    uint4 bufA[4][2], bufB[4][2];
    LOAD_SG(bufA, from);
    for (int ug = from; ug < to; ug += 32) {
        LOAD_SG(bufB, ug + 16);
        PROC_SG(bufA, ug);
        if (ug + 32 < to) LOAD_SG(bufA, ug + 32);
        PROC_SG(bufB, ug + 16);
    }
}

__global__ __launch_bounds__(64) void scan_kernel(const unsigned short* __restrict__ rect,
                                                  float* __restrict__ out) {
    const int c    = threadIdx.x;                       // channel
    const int u0   = blockIdx.x * CT;                   // global step in [0, 96000)
    const int uend = min(u0 + CT, 2 * T_LEN);
    const int w0   = (u0 >= WU) ? (u0 - WU) : 0;
    float s0 = 0.f, s1 = 0.f, s2 = 0.f, s3 = 0.f, thr = 0.1f;
    float* out0 = out;
    float* out1 = out + (size_t)NB * T_LEN * 2 * NCH;   // 24,576,000
    scan_range<false>(w0, u0,   c, rect, out0, out1, s0, s1, s2, s3, thr);
    scan_range<true >(u0, uend, c, rect, out0, out1, s0, s1, s2, s3, thr);
}

// ---------------------------------------------------------------- launch
extern "C" void kernel_launch(void* const* d_in, const int* in_sizes, int n_in,
                              void* d_out, int out_size, void* d_ws, size_t ws_size,
                              hipStream_t stream) {
    const float* x  = (const float*)d_in[0];       // [4, 48000] fp32
    const float* Km = (const float*)d_in[1];       // [64, L]    fp32
    const int L     = in_sizes[1] / NCH;
    const int SMAX  = (L + 31) / 32;
    const int PAD   = (L + 1) & ~1;                // even, >= L-1
    const int XCAP  = PAD + T_LEN + 64;            // even

    char* w = (char*)d_ws;
    int* kstart = (int*)w;
    unsigned short* xc = (unsigned short*)(w + 512);
    const size_t xc_bytes = (size_t)NB * 2 * XCAP * 2;
    unsigned short* Afrag = (unsigned short*)(w + 512 + ((xc_bytes + 15) & ~(size_t)15));
    const size_t a_bytes = (size_t)4 * SMAX * 64 * 8 * 2;
    unsigned short* rect = (unsigned short*)((char*)Afrag + ((a_bytes + 15) & ~(size_t)15));

    kstart_kernel<<<NCH, 256, 0, stream>>>(Km, kstart, L);
    prep_x<<<(NB * XCAP + 255) / 256, 256, 0, stream>>>(x, xc, PAD, XCAP);
    prep_a<<<dim3(SMAX, 4), 64, 0, stream>>>(Km, kstart, Afrag, L, SMAX);
    conv_mfma<<<dim3(T_LEN / 64, 4), 256, 0, stream>>>(xc, Afrag, kstart, rect, L, SMAX, PAD, XCAP);
    scan_kernel<<<(2 * T_LEN) / CT, 64, 0, stream>>>(rect, (float*)d_out);
}

// Round 3
// 130.743 us; speedup vs baseline: 5.2893x; 1.1834x over previous
//
#include <hip/hip_runtime.h>
#include <hip/hip_bf16.h>

#define T_LEN 48000
#define NCH   64
#define NB    4
#define CT    256    // scan chunk length
#define WU    384    // scan warm-up steps (0.96^384~2e-7, 0.99^384~0.021 -> spike flips only)

static constexpr double DTd    = 1.0 / 48000.0;
static constexpr double ALPHAd = DTd / (DTd + 0.0005);   // exactly 0.04
static constexpr float  AF     = (float)ALPHAd;
static constexpr float  OMF    = (float)(1.0 - ALPHAd);  // 0.96

typedef __attribute__((ext_vector_type(8))) short bf16x8;
typedef __attribute__((ext_vector_type(4))) float f32x4;
typedef bf16x8 bf16x8_u __attribute__((aligned(4)));     // 4B-aligned 16B load

static __device__ __forceinline__ unsigned short f2bf(float f) {
    __hip_bfloat16 h = __float2bfloat16(f);
    unsigned short u; __builtin_memcpy(&u, &h, 2);
    return u;
}

// ---------------------------------------------------------------- K0: first nonzero tap per channel
__global__ void kstart_kernel(const float* __restrict__ Km, int* __restrict__ kstart, int L) {
    __shared__ int smin;
    if (threadIdx.x == 0) smin = L - 1;
    __syncthreads();
    const int c = blockIdx.x;
    int local = L - 1;
    for (int i = threadIdx.x; i < L; i += blockDim.x) {
        if (Km[(size_t)c * L + i] != 0.0f) { local = i; break; }
    }
    atomicMin(&smin, local);
    __syncthreads();
    if (threadIdx.x == 0) kstart[c] = smin;
}

// ---------------------------------------------------------------- K1a: x -> two parity-shifted bf16 copies (zero padded)
__global__ void prep_x(const float* __restrict__ x, unsigned short* __restrict__ xc,
                       int PAD, int XCAP) {
    const int idx = blockIdx.x * 256 + threadIdx.x;
    if (idx >= NB * XCAP) return;
    const int b = idx / XCAP, j = idx % XCAP;
    const float* xb = x + (size_t)b * T_LEN;
    const int t0 = j - PAD, t1 = t0 + 1;
    xc[((size_t)b * 2 + 0) * XCAP + j] = (t0 >= 0 && t0 < T_LEN) ? f2bf(xb[t0]) : (unsigned short)0;
    xc[((size_t)b * 2 + 1) * XCAP + j] = (t1 >= 0 && t1 < T_LEN) ? f2bf(xb[t1]) : (unsigned short)0;
}

// ---------------------------------------------------------------- K1b: kernels -> pre-swizzled bf16 A-fragments
// Afrag[g][s][lane][j] = K[g*16 + (lane&15)][ks_g + 32s + 8*(lane>>4) + j]  (0 beyond Lg)
__global__ void prep_a(const float* __restrict__ Km, const int* __restrict__ kstart,
                       unsigned short* __restrict__ Afrag, int L, int SMAX4) {
    const int s = blockIdx.x, g = blockIdx.y, lane = threadIdx.x;
    const int ks = kstart[g * 16];
    const int Lg = L - ks;
    const int r = lane & 15, khi = lane >> 4;
    const float* kr = Km + (size_t)(g * 16 + r) * L + ks;
    const size_t off = ((size_t)(g * SMAX4 + s) * 64 + lane) * 8;
    #pragma unroll
    for (int jj = 0; jj < 8; ++jj) {
        const int q = 32 * s + 8 * khi + jj;
        Afrag[off + jj] = (q < Lg) ? f2bf(kr[q]) : (unsigned short)0;
    }
}

// ---------------------------------------------------------------- K2: MFMA filterbank -> rect bf16 [B][C][T]
// block: (t-tile of 128, group); wave = one batch, 8 time-tiles of 16.
// Toeplitz register reuse: B(j+2, s) == B(j, s+1) -> 8-slot rolling window,
// only 2 new B-loads + 1 A-load per K-step (8 MFMA).
__global__ __launch_bounds__(256) void conv_mfma(
        const unsigned short* __restrict__ xc, const unsigned short* __restrict__ Afrag,
        const int* __restrict__ kstart, unsigned short* __restrict__ rect,
        int L, int SMAX4, int PAD, int XCAP) {
    const int lane = threadIdx.x & 63;
    const int b    = threadIdx.x >> 6;
    const int g    = blockIdx.y;
    const int t0   = blockIdx.x * 128;
    const int ks   = kstart[g * 16];
    const int Lg   = L - ks;
    const int nst4 = (((Lg + 31) >> 5) + 3) & ~3;      // K-steps, padded to x4 (A zero-padded)
    const int nl   = lane & 15, khi = lane >> 4;
    const int i0   = t0 + nl + 8 * khi - (Lg - 1);     // x index for (s=0, tile 0)
    const int p    = i0 & 1;                           // parity fixed across s and tiles
    const unsigned short* xp = xc + ((size_t)(b * 2 + p)) * XCAP + (PAD + i0 - p);
    const unsigned short* ap = Afrag + ((size_t)(g * SMAX4) * 64 + (size_t)lane) * 8;

    f32x4 acc[8];
    #pragma unroll
    for (int j = 0; j < 8; ++j) acc[j] = (f32x4){0.f, 0.f, 0.f, 0.f};
    bf16x8 bx[8];
    #pragma unroll
    for (int j = 0; j < 8; ++j) bx[j] = *(const bf16x8_u*)(xp + 16 * j);

    for (int s = 0; s < nst4; s += 4) {
        #pragma unroll
        for (int u = 0; u < 4; ++u) {
            const bf16x8 av = *(const bf16x8*)(ap + u * 512);
            #pragma unroll
            for (int j = 0; j < 8; ++j)
                acc[j] = __builtin_amdgcn_mfma_f32_16x16x32_bf16(av, bx[(2 * u + j) & 7], acc[j], 0, 0, 0);
            // refill the two consumed slots with windows 2u+8, 2u+9
            bx[(2 * u)     & 7] = *(const bf16x8_u*)(xp + u * 32 + 128);
            bx[(2 * u + 1) & 7] = *(const bf16x8_u*)(xp + u * 32 + 144);
        }
        xp += 128; ap += 2048;
    }

    // D layout: col(time)=lane&15, row(channel)=4*(lane>>4)+v   [m89-verified]
    unsigned short* rp = rect + (size_t)(b * NCH + g * 16 + 4 * khi) * T_LEN + t0 + nl;
    #pragma unroll
    for (int j = 0; j < 8; ++j) {
        #pragma unroll
        for (int v = 0; v < 4; ++v)
            rp[(size_t)v * T_LEN + 16 * j] = f2bf(fmaxf(acc[j][v], 0.f));
    }
}

// ---------------------------------------------------------------- K3: fused EMA + adaptive-threshold scan
static __device__ __forceinline__ float bfw(unsigned int w, int odd) {
    return __uint_as_float(odd ? (w & 0xFFFF0000u) : (w << 16));
}
static __device__ __forceinline__ unsigned int getw(const uint4& u, int i) {
    return i == 0 ? u.x : i == 1 ? u.y : i == 2 ? u.z : u.w;  // i is compile-time
}

__device__ __forceinline__ void scan_step(float r0, float r1, float r2, float r3,
        int u, bool store, int c, float* __restrict__ out0, float* __restrict__ out1,
        float& s0, float& s1, float& s2, float& s3, float& thr) {
    s0 = AF * r0 + OMF * s0;
    s1 = AF * r1 + OMF * s1;
    s2 = AF * r2 + OMF * s2;
    s3 = AF * r3 + OMF * s3;
    const float k0 = (s0 > thr) ? 1.0f : 0.0f;
    const float k1 = (s1 > thr) ? 1.0f : 0.0f;
    const float k2 = (s2 > thr) ? 1.0f : 0.0f;
    const float k3 = (s3 > thr) ? 1.0f : 0.0f;
    const float cnt = (k0 + k1) + (k2 + k3);
    thr = thr + 0.01f * (cnt * 0.25f) + 0.01f * (0.1f - thr);
    if (store) {
        const int e  = (u >= T_LEN) ? 1 : 0;
        const int tt = u - (e ? T_LEN : 0);
        const int o1 = ((e * T_LEN + tt) << 6) + c;          // [B][2][T][C]
        out1[o1]                   = s0;
        out1[o1 + 2 * T_LEN * NCH] = s1;
        out1[o1 + 4 * T_LEN * NCH] = s2;
        out1[o1 + 6 * T_LEN * NCH] = s3;
        const int o0 = (tt << 7) + (e << 6) + c;             // [B][T][2C]
        out0[o0]                   = k0;
        out0[o0 + T_LEN * 128]     = k1;
        out0[o0 + 2 * T_LEN * 128] = k2;
        out0[o0 + 3 * T_LEN * 128] = k3;
    }
}

#define LOAD_SG(buf, ug) do {                                                          \
    const int tt_ = ((ug) < T_LEN) ? (ug) : ((ug) - T_LEN);                            \
    _Pragma("unroll")                                                                  \
    for (int b_ = 0; b_ < 4; ++b_) {                                                   \
        const uint4* p_ = (const uint4*)(rect + (size_t)(b_ * NCH + c) * T_LEN + tt_); \
        buf[b_][0] = p_[0];                                                            \
        buf[b_][1] = p_[1];                                                            \
    }                                                                                  \
} while (0)

#define PROC_SG(buf, ug) do {                                                          \
    _Pragma("unroll")                                                                  \
    for (int q_ = 0; q_ < 16; ++q_) {                                                  \
        const float r0_ = bfw(getw(buf[0][q_ >> 3], (q_ >> 1) & 3), q_ & 1);           \
        const float r1_ = bfw(getw(buf[1][q_ >> 3], (q_ >> 1) & 3), q_ & 1);           \
        const float r2_ = bfw(getw(buf[2][q_ >> 3], (q_ >> 1) & 3), q_ & 1);           \
        const float r3_ = bfw(getw(buf[3][q_ >> 3], (q_ >> 1) & 3), q_ & 1);           \
        scan_step(r0_, r1_, r2_, r3_, (ug) + q_, STORE, c, out0, out1, s0, s1, s2, s3, thr); \
    }                                                                                  \
} while (0)

template <bool STORE>
__device__ __forceinline__ void scan_range(int from, int to, int c,
        const unsigned short* __restrict__ rect, float* __restrict__ out0, float* __restrict__ out1,
        float& s0, float& s1, float& s2, float& s3, float& thr) {
    if (from >= to) return;                // (to-from) is a multiple of 32
    uint4 bufA[4][2], bufB[4][2];
    LOAD_SG(bufA, from);
    for (int ug = from; ug < to; ug += 32) {
        LOAD_SG(bufB, ug + 16);
        PROC_SG(bufA, ug);
        if (ug + 32 < to) LOAD_SG(bufA, ug + 32);
        PROC_SG(bufB, ug + 16);
    }
}

__global__ __launch_bounds__(64) void scan_kernel(const unsigned short* __restrict__ rect,
                                                  float* __restrict__ out) {
    const int c    = threadIdx.x;                       // channel
    const int u0   = blockIdx.x * CT;                   // global step in [0, 96000)
    const int uend = min(u0 + CT, 2 * T_LEN);
    const int w0   = (u0 >= WU) ? (u0 - WU) : 0;
    float s0 = 0.f, s1 = 0.f, s2 = 0.f, s3 = 0.f, thr = 0.1f;
    float* out0 = out;
    float* out1 = out + (size_t)NB * T_LEN * 2 * NCH;   // 24,576,000
    scan_range<false>(w0, u0,   c, rect, out0, out1, s0, s1, s2, s3, thr);
    scan_range<true >(u0, uend, c, rect, out0, out1, s0, s1, s2, s3, thr);
}

// ---------------------------------------------------------------- launch
extern "C" void kernel_launch(void* const* d_in, const int* in_sizes, int n_in,
                              void* d_out, int out_size, void* d_ws, size_t ws_size,
                              hipStream_t stream) {
    const float* x  = (const float*)d_in[0];       // [4, 48000] fp32
    const float* Km = (const float*)d_in[1];       // [64, L]    fp32
    const int L     = in_sizes[1] / NCH;
    const int SMAX  = (L + 31) / 32;
    const int SMAX4 = (SMAX + 3) & ~3;
    const int PAD   = (L + 1) & ~1;                // even, >= L-1
    const int XCAP  = PAD + T_LEN + 512;           // even; +512 covers padded-K over-read

    char* w = (char*)d_ws;
    int* kstart = (int*)w;
    unsigned short* xc = (unsigned short*)(w + 512);
    const size_t xc_bytes = (size_t)NB * 2 * XCAP * 2;
    unsigned short* Afrag = (unsigned short*)(w + 512 + ((xc_bytes + 15) & ~(size_t)15));
    const size_t a_bytes = (size_t)4 * SMAX4 * 64 * 8 * 2;
    unsigned short* rect = (unsigned short*)((char*)Afrag + ((a_bytes + 15) & ~(size_t)15));

    kstart_kernel<<<NCH, 256, 0, stream>>>(Km, kstart, L);
    prep_x<<<(NB * XCAP + 255) / 256, 256, 0, stream>>>(x, xc, PAD, XCAP);
    prep_a<<<dim3(SMAX4, 4), 64, 0, stream>>>(Km, kstart, Afrag, L, SMAX4);
    conv_mfma<<<dim3(T_LEN / 128, 4), 256, 0, stream>>>(xc, Afrag, kstart, rect, L, SMAX4, PAD, XCAP);
    scan_kernel<<<(2 * T_LEN) / CT, 64, 0, stream>>>(rect, (float*)d_out);
}

// Round 4
// 119.532 us; speedup vs baseline: 5.7854x; 1.0938x over previous
//
#include <hip/hip_runtime.h>
#include <hip/hip_bf16.h>

#define T_LEN 48000
#define NCH   64
#define NB    4
#define CT    256    // scan chunk length
#define WU    256    // scan warm-up steps (0.96^256~2.9e-5; thr err -> spike flips only)

static constexpr double DTd    = 1.0 / 48000.0;
static constexpr double ALPHAd = DTd / (DTd + 0.0005);   // exactly 0.04
static constexpr float  AF     = (float)ALPHAd;
static constexpr float  OMF    = (float)(1.0 - ALPHAd);  // 0.96

typedef __attribute__((ext_vector_type(8))) short bf16x8;
typedef __attribute__((ext_vector_type(4))) float f32x4;
typedef bf16x8 bf16x8_u __attribute__((aligned(4)));     // 4B-aligned 16B load

static __device__ __forceinline__ unsigned short f2bf(float f) {
    __hip_bfloat16 h = __float2bfloat16(f);
    unsigned short u; __builtin_memcpy(&u, &h, 2);
    return u;
}

// ---------------------------------------------------------------- K0: fused prep
// role (blockIdx.y) 0..3: Afrag swizzle for group g (+kstart[g*16]); role 4: x -> bf16 copies
__global__ __launch_bounds__(256) void prep_all(
        const float* __restrict__ x, const float* __restrict__ Km,
        int* __restrict__ kstart, unsigned short* __restrict__ xc,
        unsigned short* __restrict__ Afrag,
        int L, int SMAX4, int SMAXA, int PAD, int XCAP) {
    const int role = blockIdx.y;
    if (role < 4) {
        const int g = role, s = blockIdx.x;
        if (s >= SMAX4) return;
        // per-block first-nonzero scan of row g*16 (L2-cached, cheap)
        __shared__ int smin;
        if (threadIdx.x == 0) smin = L - 1;
        __syncthreads();
        const float* row = Km + (size_t)(g * 16) * L;
        int local = L - 1;
        for (int i = threadIdx.x; i < L; i += 256)
            if (row[i] != 0.0f) { local = i; break; }
        atomicMin(&smin, local);
        __syncthreads();
        const int ks = smin;
        if (s == 0 && threadIdx.x == 0) kstart[g * 16] = ks;
        if (threadIdx.x < 64) {
            const int lane = threadIdx.x;
            const int Lg = L - ks;
            const int r = lane & 15, khi = lane >> 4;
            const float* kr = Km + (size_t)(g * 16 + r) * L + ks;
            const size_t off = ((size_t)(g * SMAXA + s) * 64 + lane) * 8;
            #pragma unroll
            for (int jj = 0; jj < 8; ++jj) {
                const int q = 32 * s + 8 * khi + jj;
                Afrag[off + jj] = (q < Lg) ? f2bf(kr[q]) : (unsigned short)0;
            }
        }
    } else {
        const int idx = blockIdx.x * 256 + threadIdx.x;
        if (idx >= NB * XCAP) return;
        const int b = idx / XCAP, j = idx % XCAP;
        const float* xb = x + (size_t)b * T_LEN;
        const int t0 = j - PAD, t1 = t0 + 1;
        xc[((size_t)b * 2 + 0) * XCAP + j] = (t0 >= 0 && t0 < T_LEN) ? f2bf(xb[t0]) : (unsigned short)0;
        xc[((size_t)b * 2 + 1) * XCAP + j] = (t1 >= 0 && t1 < T_LEN) ? f2bf(xb[t1]) : (unsigned short)0;
    }
}

// ---------------------------------------------------------------- K1: MFMA filterbank -> rect bf16 [B][C][T]
// Toeplitz register reuse (B(j+2,s)==B(j,s+1)) + double-buffered A-frag prefetch.
__global__ __launch_bounds__(256) void conv_mfma(
        const unsigned short* __restrict__ xc, const unsigned short* __restrict__ Afrag,
        const int* __restrict__ kstart, unsigned short* __restrict__ rect,
        int L, int SMAXA, int PAD, int XCAP) {
    const int lane = threadIdx.x & 63;
    const int b    = threadIdx.x >> 6;
    const int g    = blockIdx.y;
    const int t0   = blockIdx.x * 128;
    const int ks   = kstart[g * 16];
    const int Lg   = L - ks;
    const int nst4 = (((Lg + 31) >> 5) + 3) & ~3;      // K-steps, padded to x4 (A zero-padded)
    const int nl   = lane & 15, khi = lane >> 4;
    const int i0   = t0 + nl + 8 * khi - (Lg - 1);     // x index for (s=0, tile 0)
    const int p    = i0 & 1;                           // parity fixed across s and tiles
    const unsigned short* xp = xc + ((size_t)(b * 2 + p)) * XCAP + (PAD + i0 - p);
    const unsigned short* ap = Afrag + ((size_t)g * SMAXA * 64 + (size_t)lane) * 8;

    f32x4 acc[8];
    #pragma unroll
    for (int j = 0; j < 8; ++j) acc[j] = (f32x4){0.f, 0.f, 0.f, 0.f};
    bf16x8 bx[8];
    #pragma unroll
    for (int j = 0; j < 8; ++j) bx[j] = *(const bf16x8_u*)(xp + 16 * j);

    bf16x8 a0 = *(const bf16x8*)(ap);
    bf16x8 a1 = *(const bf16x8*)(ap + 512);
    bf16x8 a2 = *(const bf16x8*)(ap + 1024);
    bf16x8 a3 = *(const bf16x8*)(ap + 1536);

    for (int s = 0; s < nst4; s += 4) {
        ap += 2048;
        // prefetch next s-block's A-frags (guard rows exist; last prefetch unused)
        const bf16x8 n0 = *(const bf16x8*)(ap);
        const bf16x8 n1 = *(const bf16x8*)(ap + 512);
        const bf16x8 n2 = *(const bf16x8*)(ap + 1024);
        const bf16x8 n3 = *(const bf16x8*)(ap + 1536);
        #pragma unroll
        for (int j = 0; j < 8; ++j)
            acc[j] = __builtin_amdgcn_mfma_f32_16x16x32_bf16(a0, bx[j & 7], acc[j], 0, 0, 0);
        bx[0] = *(const bf16x8_u*)(xp + 128);
        bx[1] = *(const bf16x8_u*)(xp + 144);
        #pragma unroll
        for (int j = 0; j < 8; ++j)
            acc[j] = __builtin_amdgcn_mfma_f32_16x16x32_bf16(a1, bx[(2 + j) & 7], acc[j], 0, 0, 0);
        bx[2] = *(const bf16x8_u*)(xp + 160);
        bx[3] = *(const bf16x8_u*)(xp + 176);
        #pragma unroll
        for (int j = 0; j < 8; ++j)
            acc[j] = __builtin_amdgcn_mfma_f32_16x16x32_bf16(a2, bx[(4 + j) & 7], acc[j], 0, 0, 0);
        bx[4] = *(const bf16x8_u*)(xp + 192);
        bx[5] = *(const bf16x8_u*)(xp + 208);
        #pragma unroll
        for (int j = 0; j < 8; ++j)
            acc[j] = __builtin_amdgcn_mfma_f32_16x16x32_bf16(a3, bx[(6 + j) & 7], acc[j], 0, 0, 0);
        bx[6] = *(const bf16x8_u*)(xp + 224);
        bx[7] = *(const bf16x8_u*)(xp + 240);
        a0 = n0; a1 = n1; a2 = n2; a3 = n3;
        xp += 128;
    }

    // D layout: col(time)=lane&15, row(channel)=4*(lane>>4)+v   [m89-verified]
    unsigned short* rp = rect + (size_t)(b * NCH + g * 16 + 4 * khi) * T_LEN + t0 + nl;
    #pragma unroll
    for (int j = 0; j < 8; ++j) {
        #pragma unroll
        for (int v = 0; v < 4; ++v)
            rp[(size_t)v * T_LEN + 16 * j] = f2bf(fmaxf(acc[j][v], 0.f));
    }
}

// ---------------------------------------------------------------- K2: fused EMA + adaptive-threshold scan
static __device__ __forceinline__ float bfw(unsigned int w, int odd) {
    return __uint_as_float(odd ? (w & 0xFFFF0000u) : (w << 16));
}
static __device__ __forceinline__ unsigned int getw(const uint4& u, int i) {
    return i == 0 ? u.x : i == 1 ? u.y : i == 2 ? u.z : u.w;  // i is compile-time
}

__device__ __forceinline__ void scan_step(float r0, float r1, float r2, float r3,
        int u, bool store, int c, float* __restrict__ out0, float* __restrict__ out1,
        float& s0, float& s1, float& s2, float& s3, float& thr) {
    s0 = AF * r0 + OMF * s0;
    s1 = AF * r1 + OMF * s1;
    s2 = AF * r2 + OMF * s2;
    s3 = AF * r3 + OMF * s3;
    const float k0 = (s0 > thr) ? 1.0f : 0.0f;
    const float k1 = (s1 > thr) ? 1.0f : 0.0f;
    const float k2 = (s2 > thr) ? 1.0f : 0.0f;
    const float k3 = (s3 > thr) ? 1.0f : 0.0f;
    const float cnt = (k0 + k1) + (k2 + k3);
    thr = thr + 0.01f * (cnt * 0.25f) + 0.01f * (0.1f - thr);
    if (store) {
        const int e  = (u >= T_LEN) ? 1 : 0;
        const int tt = u - (e ? T_LEN : 0);
        const int o1 = ((e * T_LEN + tt) << 6) + c;          // [B][2][T][C]
        out1[o1]                   = s0;
        out1[o1 + 2 * T_LEN * NCH] = s1;
        out1[o1 + 4 * T_LEN * NCH] = s2;
        out1[o1 + 6 * T_LEN * NCH] = s3;
        const int o0 = (tt << 7) + (e << 6) + c;             // [B][T][2C]
        out0[o0]                   = k0;
        out0[o0 + T_LEN * 128]     = k1;
        out0[o0 + 2 * T_LEN * 128] = k2;
        out0[o0 + 3 * T_LEN * 128] = k3;
    }
}

#define LOAD_SG(buf, ug) do {                                                          \
    const int tt_ = ((ug) < T_LEN) ? (ug) : ((ug) - T_LEN);                            \
    _Pragma("unroll")                                                                  \
    for (int b_ = 0; b_ < 4; ++b_) {                                                   \
        const uint4* p_ = (const uint4*)(rect + (size_t)(b_ * NCH + c) * T_LEN + tt_); \
        buf[b_][0] = p_[0];                                                            \
        buf[b_][1] = p_[1];                                                            \
    }                                                                                  \
} while (0)

#define PROC_SG(buf, ug) do {                                                          \
    _Pragma("unroll")                                                                  \
    for (int q_ = 0; q_ < 16; ++q_) {                                                  \
        const float r0_ = bfw(getw(buf[0][q_ >> 3], (q_ >> 1) & 3), q_ & 1);           \
        const float r1_ = bfw(getw(buf[1][q_ >> 3], (q_ >> 1) & 3), q_ & 1);           \
        const float r2_ = bfw(getw(buf[2][q_ >> 3], (q_ >> 1) & 3), q_ & 1);           \
        const float r3_ = bfw(getw(buf[3][q_ >> 3], (q_ >> 1) & 3), q_ & 1);           \
        scan_step(r0_, r1_, r2_, r3_, (ug) + q_, STORE, c, out0, out1, s0, s1, s2, s3, thr); \
    }                                                                                  \
} while (0)

template <bool STORE>
__device__ __forceinline__ void scan_range(int from, int to, int c,
        const unsigned short* __restrict__ rect, float* __restrict__ out0, float* __restrict__ out1,
        float& s0, float& s1, float& s2, float& s3, float& thr) {
    if (from >= to) return;                // (to-from) is a multiple of 32
    uint4 bufA[4][2], bufB[4][2];
    LOAD_SG(bufA, from);
    for (int ug = from; ug < to; ug += 32) {
        LOAD_SG(bufB, ug + 16);
        PROC_SG(bufA, ug);
        if (ug + 32 < to) LOAD_SG(bufA, ug + 32);
        PROC_SG(bufB, ug + 16);
    }
}

__global__ __launch_bounds__(64) void scan_kernel(const unsigned short* __restrict__ rect,
                                                  float* __restrict__ out) {
    const int c    = threadIdx.x;                       // channel
    const int u0   = blockIdx.x * CT;                   // global step in [0, 96000)
    const int uend = min(u0 + CT, 2 * T_LEN);
    const int w0   = (u0 >= WU) ? (u0 - WU) : 0;
    float s0 = 0.f, s1 = 0.f, s2 = 0.f, s3 = 0.f, thr = 0.1f;
    float* out0 = out;
    float* out1 = out + (size_t)NB * T_LEN * 2 * NCH;   // 24,576,000
    scan_range<false>(w0, u0,   c, rect, out0, out1, s0, s1, s2, s3, thr);
    scan_range<true >(u0, uend, c, rect, out0, out1, s0, s1, s2, s3, thr);
}

// ---------------------------------------------------------------- launch
extern "C" void kernel_launch(void* const* d_in, const int* in_sizes, int n_in,
                              void* d_out, int out_size, void* d_ws, size_t ws_size,
                              hipStream_t stream) {
    const float* x  = (const float*)d_in[0];       // [4, 48000] fp32
    const float* Km = (const float*)d_in[1];       // [64, L]    fp32
    const int L     = in_sizes[1] / NCH;
    const int SMAX  = (L + 31) / 32;
    const int SMAX4 = (SMAX + 3) & ~3;
    const int SMAXA = SMAX4 + 4;                   // +4-block guard for A prefetch
    const int PAD   = (L + 1) & ~1;                // even, >= L-1
    const int XCAP  = PAD + T_LEN + 512;           // even; covers padded-K over-read

    char* w = (char*)d_ws;
    int* kstart = (int*)w;
    unsigned short* xc = (unsigned short*)(w + 512);
    const size_t xc_bytes = (size_t)NB * 2 * XCAP * 2;
    unsigned short* Afrag = (unsigned short*)(w + 512 + ((xc_bytes + 15) & ~(size_t)15));
    const size_t a_bytes = (size_t)4 * SMAXA * 64 * 8 * 2;
    unsigned short* rect = (unsigned short*)((char*)Afrag + ((a_bytes + 15) & ~(size_t)15));

    const int pxBlocks = (NB * XCAP + 255) / 256;
    dim3 pgrid(pxBlocks > SMAX4 ? pxBlocks : SMAX4, 5);
    prep_all<<<pgrid, 256, 0, stream>>>(x, Km, kstart, xc, Afrag, L, SMAX4, SMAXA, PAD, XCAP);
    conv_mfma<<<dim3(T_LEN / 128, 4), 256, 0, stream>>>(xc, Afrag, kstart, rect, L, SMAXA, PAD, XCAP);
    scan_kernel<<<(2 * T_LEN) / CT, 64, 0, stream>>>(rect, (float*)d_out);
}

// Round 5
// 117.781 us; speedup vs baseline: 5.8714x; 1.0149x over previous
//
#include <hip/hip_runtime.h>
#include <hip/hip_bf16.h>

#define T_LEN 48000
#define NCH   64
#define NB    4
#define CT    256    // scan chunk length
#define WU    256    // scan warm-up steps (0.96^256~2.9e-5; thr err -> spike flips only)

static constexpr double DTd    = 1.0 / 48000.0;
static constexpr double ALPHAd = DTd / (DTd + 0.0005);   // exactly 0.04
static constexpr float  AF     = (float)ALPHAd;
static constexpr float  OMF    = (float)(1.0 - ALPHAd);  // 0.96

typedef __attribute__((ext_vector_type(8))) short bf16x8;
typedef __attribute__((ext_vector_type(4))) float f32x4;
typedef bf16x8 bf16x8_u __attribute__((aligned(4)));     // 4B-aligned 16B load

static __device__ __forceinline__ unsigned short f2bf(float f) {
    __hip_bfloat16 h = __float2bfloat16(f);
    unsigned short u; __builtin_memcpy(&u, &h, 2);
    return u;
}

// ---------------------------------------------------------------- K0: fused prep
// role (blockIdx.y) 0..3: Afrag swizzle for group g (+kstart[g*16]); role 4: x -> bf16 copies
__global__ __launch_bounds__(256) void prep_all(
        const float* __restrict__ x, const float* __restrict__ Km,
        int* __restrict__ kstart, unsigned short* __restrict__ xc,
        unsigned short* __restrict__ Afrag,
        int L, int SMAX4, int SMAXA, int PAD, int XCAP) {
    const int role = blockIdx.y;
    if (role < 4) {
        const int g = role, s = blockIdx.x;
        if (s >= SMAX4) return;
        // per-block first-nonzero scan of row g*16 (L2-cached, cheap)
        __shared__ int smin;
        if (threadIdx.x == 0) smin = L - 1;
        __syncthreads();
        const float* row = Km + (size_t)(g * 16) * L;
        int local = L - 1;
        for (int i = threadIdx.x; i < L; i += 256)
            if (row[i] != 0.0f) { local = i; break; }
        atomicMin(&smin, local);
        __syncthreads();
        const int ks = smin;
        if (s == 0 && threadIdx.x == 0) kstart[g * 16] = ks;
        if (threadIdx.x < 64) {
            const int lane = threadIdx.x;
            const int Lg = L - ks;
            const int r = lane & 15, khi = lane >> 4;
            const float* kr = Km + (size_t)(g * 16 + r) * L + ks;
            const size_t off = ((size_t)(g * SMAXA + s) * 64 + lane) * 8;
            #pragma unroll
            for (int jj = 0; jj < 8; ++jj) {
                const int q = 32 * s + 8 * khi + jj;
                Afrag[off + jj] = (q < Lg) ? f2bf(kr[q]) : (unsigned short)0;
            }
        }
    } else {
        const int idx = blockIdx.x * 256 + threadIdx.x;
        if (idx >= NB * XCAP) return;
        const int b = idx / XCAP, j = idx % XCAP;
        const float* xb = x + (size_t)b * T_LEN;
        const int t0 = j - PAD, t1 = t0 + 1;
        xc[((size_t)b * 2 + 0) * XCAP + j] = (t0 >= 0 && t0 < T_LEN) ? f2bf(xb[t0]) : (unsigned short)0;
        xc[((size_t)b * 2 + 1) * XCAP + j] = (t1 >= 0 && t1 < T_LEN) ? f2bf(xb[t1]) : (unsigned short)0;
    }
}

// ---------------------------------------------------------------- K1: MFMA filterbank -> rect bf16 [B][C][T]
// Toeplitz register reuse (B(j+2,s)==B(j,s+1)); A-fragments staged through
// double-buffered LDS, shared by the 4 waves (4x less A L1-traffic, -32 VGPR).
__global__ __launch_bounds__(256) void conv_mfma(
        const unsigned short* __restrict__ xc, const unsigned short* __restrict__ Afrag,
        const int* __restrict__ kstart, unsigned short* __restrict__ rect,
        int L, int SMAXA, int PAD, int XCAP) {
    const int lane = threadIdx.x & 63;
    const int w    = threadIdx.x >> 6;                 // wave = batch
    const int g    = blockIdx.y;
    const int t0   = blockIdx.x * 128;
    const int ks   = kstart[g * 16];
    const int Lg   = L - ks;
    const int nst4 = (((Lg + 31) >> 5) + 3) & ~3;      // K-steps, padded to x4 (A zero-padded)
    const int nl   = lane & 15, khi = lane >> 4;
    const int i0   = t0 + nl + 8 * khi - (Lg - 1);     // x index for (s=0, tile 0)
    const int p    = i0 & 1;                           // parity fixed across s and tiles
    const unsigned short* xp = xc + ((size_t)(w * 2 + p)) * XCAP + (PAD + i0 - p);
    // wave w stages K-step row (s + w): base points at row w
    const unsigned short* ap = Afrag + ((size_t)(g * SMAXA + w) * 64 + (size_t)lane) * 8;

    __shared__ short As[2][2048];                      // [buf][4 K-steps x 64 lanes x 8]

    f32x4 acc[8];
    #pragma unroll
    for (int j = 0; j < 8; ++j) acc[j] = (f32x4){0.f, 0.f, 0.f, 0.f};
    bf16x8 bx[8];
    #pragma unroll
    for (int j = 0; j < 8; ++j) bx[j] = *(const bf16x8_u*)(xp + 16 * j);

    // initial stage: s-block 0 (wave w stages its row w)
    {
        const bf16x8 st = *(const bf16x8*)(ap);
        *(bf16x8*)(&As[0][w * 512 + lane * 8]) = st;
    }
    __syncthreads();

    int q = 0;
    for (int s = 0; s < nst4; s += 4) {
        // prefetch next s-block's A row (guard rows exist; latency hides under MFMA)
        const bf16x8 nxt = *(const bf16x8*)(ap + (size_t)(s + 4) * 512);
        // hoist the 4 A-frag ds_reads (conflict-free linear b128)
        const bf16x8 a0 = *(const bf16x8*)(&As[q][          lane * 8]);
        const bf16x8 a1 = *(const bf16x8*)(&As[q][ 512 + lane * 8]);
        const bf16x8 a2 = *(const bf16x8*)(&As[q][1024 + lane * 8]);
        const bf16x8 a3 = *(const bf16x8*)(&As[q][1536 + lane * 8]);
        #pragma unroll
        for (int j = 0; j < 8; ++j)
            acc[j] = __builtin_amdgcn_mfma_f32_16x16x32_bf16(a0, bx[j & 7], acc[j], 0, 0, 0);
        bx[0] = *(const bf16x8_u*)(xp + 128);
        bx[1] = *(const bf16x8_u*)(xp + 144);
        #pragma unroll
        for (int j = 0; j < 8; ++j)
            acc[j] = __builtin_amdgcn_mfma_f32_16x16x32_bf16(a1, bx[(2 + j) & 7], acc[j], 0, 0, 0);
        bx[2] = *(const bf16x8_u*)(xp + 160);
        bx[3] = *(const bf16x8_u*)(xp + 176);
        #pragma unroll
        for (int j = 0; j < 8; ++j)
            acc[j] = __builtin_amdgcn_mfma_f32_16x16x32_bf16(a2, bx[(4 + j) & 7], acc[j], 0, 0, 0);
        bx[4] = *(const bf16x8_u*)(xp + 192);
        bx[5] = *(const bf16x8_u*)(xp + 208);
        #pragma unroll
        for (int j = 0; j < 8; ++j)
            acc[j] = __builtin_amdgcn_mfma_f32_16x16x32_bf16(a3, bx[(6 + j) & 7], acc[j], 0, 0, 0);
        bx[6] = *(const bf16x8_u*)(xp + 224);
        bx[7] = *(const bf16x8_u*)(xp + 240);
        // stage next s-block into the other buffer, then block-wide handoff
        *(bf16x8*)(&As[q ^ 1][w * 512 + lane * 8]) = nxt;
        __syncthreads();
        q ^= 1;
        xp += 128;
    }

    // D layout: col(time)=lane&15, row(channel)=4*(lane>>4)+v   [m89-verified]
    unsigned short* rp = rect + (size_t)(w * NCH + g * 16 + 4 * khi) * T_LEN + t0 + nl;
    #pragma unroll
    for (int j = 0; j < 8; ++j) {
        #pragma unroll
        for (int v = 0; v < 4; ++v)
            rp[(size_t)v * T_LEN + 16 * j] = f2bf(fmaxf(acc[j][v], 0.f));
    }
}

// ---------------------------------------------------------------- K2: fused EMA + adaptive-threshold scan
static __device__ __forceinline__ float bfw(unsigned int w, int odd) {
    return __uint_as_float(odd ? (w & 0xFFFF0000u) : (w << 16));
}
static __device__ __forceinline__ unsigned int getw(const uint4& u, int i) {
    return i == 0 ? u.x : i == 1 ? u.y : i == 2 ? u.z : u.w;  // i is compile-time
}

__device__ __forceinline__ void scan_step(float r0, float r1, float r2, float r3,
        int u, bool store, int c, float* __restrict__ out0, float* __restrict__ out1,
        float& s0, float& s1, float& s2, float& s3, float& thr) {
    s0 = AF * r0 + OMF * s0;
    s1 = AF * r1 + OMF * s1;
    s2 = AF * r2 + OMF * s2;
    s3 = AF * r3 + OMF * s3;
    const float k0 = (s0 > thr) ? 1.0f : 0.0f;
    const float k1 = (s1 > thr) ? 1.0f : 0.0f;
    const float k2 = (s2 > thr) ? 1.0f : 0.0f;
    const float k3 = (s3 > thr) ? 1.0f : 0.0f;
    const float cnt = (k0 + k1) + (k2 + k3);
    thr = thr + 0.01f * (cnt * 0.25f) + 0.01f * (0.1f - thr);
    if (store) {
        const int e  = (u >= T_LEN) ? 1 : 0;
        const int tt = u - (e ? T_LEN : 0);
        const int o1 = ((e * T_LEN + tt) << 6) + c;          // [B][2][T][C]
        out1[o1]                   = s0;
        out1[o1 + 2 * T_LEN * NCH] = s1;
        out1[o1 + 4 * T_LEN * NCH] = s2;
        out1[o1 + 6 * T_LEN * NCH] = s3;
        const int o0 = (tt << 7) + (e << 6) + c;             // [B][T][2C]
        out0[o0]                   = k0;
        out0[o0 + T_LEN * 128]     = k1;
        out0[o0 + 2 * T_LEN * 128] = k2;
        out0[o0 + 3 * T_LEN * 128] = k3;
    }
}

#define LOAD_SG(buf, ug) do {                                                          \
    const int tt_ = ((ug) < T_LEN) ? (ug) : ((ug) - T_LEN);                            \
    _Pragma("unroll")                                                                  \
    for (int b_ = 0; b_ < 4; ++b_) {                                                   \
        const uint4* p_ = (const uint4*)(rect + (size_t)(b_ * NCH + c) * T_LEN + tt_); \
        buf[b_][0] = p_[0];                                                            \
        buf[b_][1] = p_[1];                                                            \
    }                                                                                  \
} while (0)

#define PROC_SG(buf, ug) do {                                                          \
    _Pragma("unroll")                                                                  \
    for (int q_ = 0; q_ < 16; ++q_) {                                                  \
        const float r0_ = bfw(getw(buf[0][q_ >> 3], (q_ >> 1) & 3), q_ & 1);           \
        const float r1_ = bfw(getw(buf[1][q_ >> 3], (q_ >> 1) & 3), q_ & 1);           \
        const float r2_ = bfw(getw(buf[2][q_ >> 3], (q_ >> 1) & 3), q_ & 1);           \
        const float r3_ = bfw(getw(buf[3][q_ >> 3], (q_ >> 1) & 3), q_ & 1);           \
        scan_step(r0_, r1_, r2_, r3_, (ug) + q_, STORE, c, out0, out1, s0, s1, s2, s3, thr); \
    }                                                                                  \
} while (0)

template <bool STORE>
__device__ __forceinline__ void scan_range(int from, int to, int c,
        const unsigned short* __restrict__ rect, float* __restrict__ out0, float* __restrict__ out1,
        float& s0, float& s1, float& s2, float& s3, float& thr) {
    if (from >= to) return;                // (to-from) is a multiple of 32
    uint4 bufA[4][2], bufB[4][2];
    LOAD_SG(bufA, from);
    for (int ug = from; ug < to; ug += 32) {
        LOAD_SG(bufB, ug + 16);
        PROC_SG(bufA, ug);
        if (ug + 32 < to) LOAD_SG(bufA, ug + 32);
        PROC_SG(bufB, ug + 16);
    }
}

__global__ __launch_bounds__(64) void scan_kernel(const unsigned short* __restrict__ rect,
                                                  float* __restrict__ out) {
    const int c    = threadIdx.x;                       // channel
    const int u0   = blockIdx.x * CT;                   // global step in [0, 96000)
    const int uend = min(u0 + CT, 2 * T_LEN);
    const int w0   = (u0 >= WU) ? (u0 - WU) : 0;
    float s0 = 0.f, s1 = 0.f, s2 = 0.f, s3 = 0.f, thr = 0.1f;
    float* out0 = out;
    float* out1 = out + (size_t)NB * T_LEN * 2 * NCH;   // 24,576,000
    scan_range<false>(w0, u0,   c, rect, out0, out1, s0, s1, s2, s3, thr);
    scan_range<true >(u0, uend, c, rect, out0, out1, s0, s1, s2, s3, thr);
}

// ---------------------------------------------------------------- launch
extern "C" void kernel_launch(void* const* d_in, const int* in_sizes, int n_in,
                              void* d_out, int out_size, void* d_ws, size_t ws_size,
                              hipStream_t stream) {
    const float* x  = (const float*)d_in[0];       // [4, 48000] fp32
    const float* Km = (const float*)d_in[1];       // [64, L]    fp32
    const int L     = in_sizes[1] / NCH;
    const int SMAX  = (L + 31) / 32;
    const int SMAX4 = (SMAX + 3) & ~3;
    const int SMAXA = SMAX4 + 4;                   // +4-row guard for A prefetch
    const int PAD   = (L + 1) & ~1;                // even, >= L-1
    const int XCAP  = PAD + T_LEN + 512;           // even; covers padded-K over-read

    char* w = (char*)d_ws;
    int* kstart = (int*)w;
    unsigned short* xc = (unsigned short*)(w + 512);
    const size_t xc_bytes = (size_t)NB * 2 * XCAP * 2;
    unsigned short* Afrag = (unsigned short*)(w + 512 + ((xc_bytes + 15) & ~(size_t)15));
    const size_t a_bytes = (size_t)4 * SMAXA * 64 * 8 * 2;
    unsigned short* rect = (unsigned short*)((char*)Afrag + ((a_bytes + 15) & ~(size_t)15));

    const int pxBlocks = (NB * XCAP + 255) / 256;
    dim3 pgrid(pxBlocks > SMAX4 ? pxBlocks : SMAX4, 5);
    prep_all<<<pgrid, 256, 0, stream>>>(x, Km, kstart, xc, Afrag, L, SMAX4, SMAXA, PAD, XCAP);
    conv_mfma<<<dim3(T_LEN / 128, 4), 256, 0, stream>>>(xc, Afrag, kstart, rect, L, SMAXA, PAD, XCAP);
    scan_kernel<<<(2 * T_LEN) / CT, 64, 0, stream>>>(rect, (float*)d_out);
}